// Round 1
// 339.708 us; speedup vs baseline: 1.1138x; 1.1138x over previous
//
#include <hip/hip_runtime.h>
#include <hip/hip_bf16.h>
#include <hip/hip_fp16.h>
#include <cmath>

// Problem constants
#define Bv   2
#define Tv   8
#define Hv   64
#define Wv   64
#define MPOS (Bv*Tv*Hv*Wv)           // 65536 positions
#define SCALEv 0.17677669529663687f  // 32^-0.5

// Attention tiling: 8x8 queries (one t, one b, one head) per block.
#define U_H   14
#define U_W   14
#define UPOS  588                    // 3*14*14 union K/V positions

// Attention LDS layout (bytes).
// Ks: 592 slots x 64 B, slot-swizzled; dest is LINEAR so global_load_lds can
//     write it directly (swizzle folded into the per-lane GLOBAL src addr).
// Vt: 32 rows x 1232 B (616 bf16 cols, d-major), XOR-swizzled by (d>>3)<<5 so
//     the 4 c-groups of a staging wave hit disjoint 8-bank groups (was 8-way).
// P : 64 rows x 1232 B (616 f16 -> bf16 in place); stride 1232 ≡ 20 dwords
//     mod 32 -> period-8 distinct row banks.
// LUT: 640 x 4 B (u -> packed f/uh/uw; pad entries u>=588 carry uh=uw=31).
// RPB: 845 f32, this head's rpb staged in phase 1 (kills the L1 gather).
#define KOFF   0
#define VTOFF  37888
#define POFF2  77312
#define LUTOFF 156160
#define RPBOFF 158720
#define SMEM_BYTES 162112            // <= 163840 -> 1 block/CU

// GEMM LDS row padding: 136 bf16 = 272 B; 272/4 = 68 dwords == 4 (mod 32)
#define KPAD 136

typedef __attribute__((ext_vector_type(8))) short bf16x8;   // MFMA A/B frag
typedef __attribute__((ext_vector_type(4))) float f32x4;    // MFMA C/D frag

__device__ __forceinline__ unsigned short f2bf16(float x) {
  return __builtin_bit_cast(unsigned short, __float2bfloat16(x));
}
__device__ __forceinline__ float bf2f(unsigned short h) {
  return __uint_as_float((unsigned)h << 16);
}
__device__ __forceinline__ float h2f(unsigned short h) {
  return __half2float(__builtin_bit_cast(__half, h));
}
__device__ __forceinline__ unsigned short f2h(float x) {
  return __builtin_bit_cast(unsigned short, __float2half(x));
}
__device__ __forceinline__ unsigned pk2(float a, float b) {
  return (unsigned)f2bf16(a) | ((unsigned)f2bf16(b) << 16);
}
// async global->LDS, 16B per lane; dest = wave-uniform base + lane*16
__device__ __forceinline__ void gload_lds16(const void* gsrc, void* ldst) {
  __builtin_amdgcn_global_load_lds(
      (const __attribute__((address_space(1))) unsigned int*)gsrc,
      (__attribute__((address_space(3))) unsigned int*)ldst, 16, 0, 0);
}

// ---------------------------------------------------------------------------
// Preconvert weights: transpose to [n][k] bf16 with KPAD row stride.
// proj_w additionally split hi/lo for the bf16x3 fp32-accurate GEMM.
// ---------------------------------------------------------------------------
__global__ __launch_bounds__(256) void preconvert(
    const float* __restrict__ qv_w, const float* __restrict__ k_w,
    const float* __restrict__ proj_w,
    ushort* __restrict__ wqvT, ushort* __restrict__ wkT,
    ushort* __restrict__ wpT_hi, ushort* __restrict__ wpT_lo) {
  const int id = blockIdx.x * 256 + threadIdx.x;
  if (id < 32768) {                       // qv: n<256, k<128
    const int n = id >> 7, kk = id & 127;
    wqvT[n * KPAD + kk] = f2bf16(qv_w[kk * 256 + n]);
  } else if (id < 49152) {                // k: n<128
    const int j = id - 32768;
    const int n = j >> 7, kk = j & 127;
    wkT[n * KPAD + kk] = f2bf16(k_w[kk * 128 + n]);
  } else {                                // proj: hi/lo split
    const int j = id - 49152;
    const int n = j >> 7, kk = j & 127;
    const float v = proj_w[kk * 128 + n];
    const unsigned short hi = f2bf16(v);
    wpT_hi[n * KPAD + kk] = hi;
    wpT_lo[n * KPAD + kk] = f2bf16(v - bf2f(hi));
  }
}

// ---------------------------------------------------------------------------
// MFMA GEMM: qv projection. 128 rows x 256 cols per block, 512 thr = 8 waves
// (wave wv owns m-strip wv*16). W staged via global_load_lds (linear copy).
// ---------------------------------------------------------------------------
__global__ __launch_bounds__(512) void gemm_qv_mfma(
    const float* __restrict__ x, const ushort* __restrict__ wqvT,
    const float* __restrict__ qv_b,
    ushort* __restrict__ qout, ushort* __restrict__ vout) {
  __shared__ ushort As[128 * KPAD];
  __shared__ ushort Ws[256 * KPAD];
  const int tid  = threadIdx.x;
  const int row0 = blockIdx.x * 128;

  // stage W async: 4352 uint4 (69632 B), 68 full wave-chunks
  {
    const uint4* wg = (const uint4*)wqvT;
    for (int i = tid; i < 4352; i += 512)
      gload_lds16(wg + i, (uint4*)Ws + i);
  }
  // stage A: 128x128 fp32 -> bf16. thread: row tid/4, cols (tid&3)*32..+31
  {
    const int r = tid >> 2, cb = (tid & 3) * 32;
    const float4* xg = (const float4*)(x + (size_t)(row0 + r) * 128 + cb);
    uint4* dst = (uint4*)(As + r * KPAD + cb);
#pragma unroll
    for (int i = 0; i < 4; ++i) {
      const float4 a = xg[2 * i], b2 = xg[2 * i + 1];
      dst[i] = make_uint4(pk2(a.x, a.y), pk2(a.z, a.w),
                          pk2(b2.x, b2.y), pk2(b2.z, b2.w));
    }
  }
  __syncthreads();

  const int wv = tid >> 6, lane = tid & 63, quad = lane >> 4, l16 = lane & 15;
  f32x4 C[16];
#pragma unroll
  for (int nt = 0; nt < 16; ++nt) C[nt] = (f32x4){0.f, 0.f, 0.f, 0.f};

#pragma unroll
  for (int kk = 0; kk < 4; ++kk) {
    const bf16x8 a = *(const bf16x8*)(As + (wv * 16 + l16) * KPAD + kk * 32 + quad * 8);
#pragma unroll
    for (int nt = 0; nt < 16; ++nt) {
      const bf16x8 b2 = *(const bf16x8*)(Ws + (nt * 16 + l16) * KPAD + kk * 32 + quad * 8);
      C[nt] = __builtin_amdgcn_mfma_f32_16x16x32_bf16(a, b2, C[nt], 0, 0, 0);
    }
  }

#pragma unroll
  for (int nt = 0; nt < 16; ++nt) {
    const int col = nt * 16 + l16;
    const float bias = qv_b[col];
#pragma unroll
    for (int r2 = 0; r2 < 4; ++r2) {
      const size_t row = row0 + wv * 16 + quad * 4 + r2;
      const float val = C[nt][r2] + bias;
      if (col < 128) qout[row * 128 + col] = f2bf16(val * SCALEv);
      else           vout[row * 128 + (col - 128)] = f2bf16(val);
    }
  }
}

// ---------------------------------------------------------------------------
// MFMA GEMM: k projection. 128 rows x 128 cols; 2 blocks/CU (70 KB LDS).
// ---------------------------------------------------------------------------
__global__ __launch_bounds__(512) void gemm_k_mfma(
    const float* __restrict__ y, const ushort* __restrict__ wkT,
    const float* __restrict__ k_b, ushort* __restrict__ kout) {
  __shared__ ushort As[128 * KPAD];
  __shared__ ushort Ws[128 * KPAD];
  const int tid  = threadIdx.x;
  const int row0 = blockIdx.x * 128;
  {
    const uint4* wg = (const uint4*)wkT;
    for (int i = tid; i < 2176; i += 512)
      gload_lds16(wg + i, (uint4*)Ws + i);
  }
  {
    const int r = tid >> 2, cb = (tid & 3) * 32;
    const float4* xg = (const float4*)(y + (size_t)(row0 + r) * 128 + cb);
    uint4* dst = (uint4*)(As + r * KPAD + cb);
#pragma unroll
    for (int i = 0; i < 4; ++i) {
      const float4 a = xg[2 * i], b2 = xg[2 * i + 1];
      dst[i] = make_uint4(pk2(a.x, a.y), pk2(a.z, a.w),
                          pk2(b2.x, b2.y), pk2(b2.z, b2.w));
    }
  }
  __syncthreads();

  const int wv = tid >> 6, lane = tid & 63, quad = lane >> 4, l16 = lane & 15;
  f32x4 C[8];
#pragma unroll
  for (int nt = 0; nt < 8; ++nt) C[nt] = (f32x4){0.f, 0.f, 0.f, 0.f};

#pragma unroll
  for (int kk = 0; kk < 4; ++kk) {
    const bf16x8 a = *(const bf16x8*)(As + (wv * 16 + l16) * KPAD + kk * 32 + quad * 8);
#pragma unroll
    for (int nt = 0; nt < 8; ++nt) {
      const bf16x8 b2 = *(const bf16x8*)(Ws + (nt * 16 + l16) * KPAD + kk * 32 + quad * 8);
      C[nt] = __builtin_amdgcn_mfma_f32_16x16x32_bf16(a, b2, C[nt], 0, 0, 0);
    }
  }

#pragma unroll
  for (int nt = 0; nt < 8; ++nt) {
    const int col = nt * 16 + l16;
    const float bias = k_b[col];
#pragma unroll
    for (int r2 = 0; r2 < 4; ++r2) {
      const size_t row = row0 + wv * 16 + quad * 4 + r2;
      kout[row * 128 + col] = f2bf16(C[nt][r2] + bias);
    }
  }
}

// ---------------------------------------------------------------------------
// MFMA GEMM: output projection, bf16x3 (fp32-accurate). 128 rows/block.
// ---------------------------------------------------------------------------
__global__ __launch_bounds__(512) void gemm_proj_mfma(
    const float* __restrict__ o, const ushort* __restrict__ wpT_hi,
    const ushort* __restrict__ wpT_lo, const float* __restrict__ proj_b,
    float* __restrict__ out) {
  __shared__ ushort Ah[128 * KPAD];
  __shared__ ushort Al[128 * KPAD];
  __shared__ ushort Wh[128 * KPAD];
  __shared__ ushort Wl[128 * KPAD];
  const int tid  = threadIdx.x;
  const int row0 = blockIdx.x * 128;
  {
    const uint4* wgh = (const uint4*)wpT_hi;
    const uint4* wgl = (const uint4*)wpT_lo;
    for (int i = tid; i < 2176; i += 512) {
      gload_lds16(wgh + i, (uint4*)Wh + i);
      gload_lds16(wgl + i, (uint4*)Wl + i);
    }
  }
  {
    const int r = tid >> 2, cb = (tid & 3) * 32;
    const float4* xg = (const float4*)(o + (size_t)(row0 + r) * 128 + cb);
    uint4* dh = (uint4*)(Ah + r * KPAD + cb);
    uint4* dl = (uint4*)(Al + r * KPAD + cb);
#pragma unroll
    for (int i = 0; i < 4; ++i) {
      const float4 a = xg[2 * i], b2 = xg[2 * i + 1];
      const float vs[8] = {a.x, a.y, a.z, a.w, b2.x, b2.y, b2.z, b2.w};
      unsigned hw[4], lw[4];
#pragma unroll
      for (int e = 0; e < 4; ++e) {
        const unsigned short h0 = f2bf16(vs[2 * e]);
        const unsigned short h1 = f2bf16(vs[2 * e + 1]);
        hw[e] = (unsigned)h0 | ((unsigned)h1 << 16);
        lw[e] = (unsigned)f2bf16(vs[2 * e] - bf2f(h0)) |
                ((unsigned)f2bf16(vs[2 * e + 1] - bf2f(h1)) << 16);
      }
      dh[i] = make_uint4(hw[0], hw[1], hw[2], hw[3]);
      dl[i] = make_uint4(lw[0], lw[1], lw[2], lw[3]);
    }
  }
  __syncthreads();

  const int wv = tid >> 6, lane = tid & 63, quad = lane >> 4, l16 = lane & 15;
  f32x4 C[8];
#pragma unroll
  for (int nt = 0; nt < 8; ++nt) C[nt] = (f32x4){0.f, 0.f, 0.f, 0.f};

#pragma unroll
  for (int kk = 0; kk < 4; ++kk) {
    const int aoff = (wv * 16 + l16) * KPAD + kk * 32 + quad * 8;
    const bf16x8 ah = *(const bf16x8*)(Ah + aoff);
    const bf16x8 al = *(const bf16x8*)(Al + aoff);
#pragma unroll
    for (int nt = 0; nt < 8; ++nt) {
      const int boff = (nt * 16 + l16) * KPAD + kk * 32 + quad * 8;
      const bf16x8 bh = *(const bf16x8*)(Wh + boff);
      const bf16x8 bl = *(const bf16x8*)(Wl + boff);
      C[nt] = __builtin_amdgcn_mfma_f32_16x16x32_bf16(ah, bh, C[nt], 0, 0, 0);
      C[nt] = __builtin_amdgcn_mfma_f32_16x16x32_bf16(ah, bl, C[nt], 0, 0, 0);
      C[nt] = __builtin_amdgcn_mfma_f32_16x16x32_bf16(al, bh, C[nt], 0, 0, 0);
    }
  }

#pragma unroll
  for (int nt = 0; nt < 8; ++nt) {
    const int col = nt * 16 + l16;
    const float bias = proj_b[col];
#pragma unroll
    for (int r2 = 0; r2 < 4; ++r2) {
      const size_t row = row0 + wv * 16 + quad * 4 + r2;
      out[row * 128 + col] = C[nt][r2] + bias;
    }
  }
}

// ---------------------------------------------------------------------------
// MFMA NA3D attention (union-GEMM). Block = 8x8 query tile (one b,t,head),
// 512 threads = 8 waves.
// ---------------------------------------------------------------------------
__global__ __launch_bounds__(512, 1)
void na3d_tile(
    const ushort* __restrict__ qin,
    const ushort* __restrict__ kin,
    const ushort* __restrict__ vin,
    const float* __restrict__ rpb,
    float* __restrict__ oout) {
  __shared__ __align__(16) unsigned char smem[SMEM_BYTES];

  const int tid  = threadIdx.x;
  const int wv   = tid >> 6;
  const int lane = tid & 63;
  const int quad = lane >> 4;
  const int l16  = lane & 15;

  const int bx   = blockIdx.x;
  const int head = bx & 3;
  const int tile = bx >> 2;
  const int w0 = (tile & 7) << 3;
  const int h0 = ((tile >> 3) & 7) << 3;
  const int t  = (tile >> 6) & 7;
  const int b  = tile >> 9;

  const int st  = min(max(t - 1, 0), Tv - 3);
  const int u_h = min(max(h0 - 3, 0), Hv - U_H);
  const int u_w = min(max(w0 - 3, 0), Wv - U_W);
  const int rt_b = st - t + 2;   // 0..2

  // ---- Phase 1 ----
  // A-frag early (plain load, waits before first MFMA)
  const int mtile = wv & 3;
  bf16x8 afrag;
  {
    const int q_a  = mtile * 16 + l16;
    const int qh_a = h0 + (q_a >> 3), qw_a = w0 + (q_a & 7);
    const size_t qpos_a = ((size_t)(b * Tv + t) * Hv + qh_a) * Wv + qw_a;
    afrag = *(const bf16x8*)(qin + qpos_a * 128 + head * 32 + quad * 8);
  }

  // rpb -> regs (issue early), write to LDS later
  float rv0 = 0.f, rv1 = 0.f;
  const int ri1 = tid + 512;
  if (tid < 845) rv0 = rpb[head * 845 + tid];
  if (ri1 < 845) rv1 = rpb[head * 845 + ri1];

  // V: issue all 5 loads per thread up front (one latency window)
  uint4 vv[5];
#pragma unroll
  for (int it = 0; it < 5; ++it) {
    const int j = tid + it * 512;          // [0, 2352)
    if (j < UPOS * 4) {
      const int pos = j >> 2, c = j & 3;
      const int ta = pos / 196;
      const int r  = pos - ta * 196;
      const int rh = r / 14;
      const int ha = u_h + rh;
      const int wa = u_w + (r - rh * 14);
      const size_t gpos = (((size_t)(b * Tv + st + ta) * Hv + ha) * Wv + wa);
      vv[it] = ((const uint4*)vin)[gpos * 16 + head * 4 + c];
    }
  }

  // K: async global->LDS, source pre-swizzled so the LDS dest is linear.
  // slot layout: dest m = pos*4 + slot holds global chunk c = (slot - pos>>2)&3
  for (int ch = wv; ch < 37; ch += 8) {
    const int m = ch * 64 + lane;          // [0, 2368)
    int pos = m >> 2;
    const int slot = m & 3;
    if (pos > UPOS - 1) pos = UPOS - 1;    // dup-load; garbage slots masked later
    const int c  = (slot - (pos >> 2)) & 3;
    const int ta = pos / 196;
    const int r  = pos - ta * 196;
    const int rh = r / 14;
    const int ha = u_h + rh;
    const int wa = u_w + (r - rh * 14);
    const size_t gpos = (((size_t)(b * Tv + st + ta) * Hv + ha) * Wv + wa);
    gload_lds16((const uint4*)kin + gpos * 16 + head * 4 + c,
                smem + KOFF + ch * 1024 + lane * 16);
  }

  // V repack -> Vt, XOR-swizzled by (d>>3)<<5 (conflict-free c-groups)
#pragma unroll
  for (int it = 0; it < 5; ++it) {
    const int j = tid + it * 512;
    if (j < UPOS * 4) {
      const int pos = j >> 2, c = j & 3;
      const unsigned sw = (unsigned)c << 5;          // d>>3 == c for this chunk
      const unsigned v4[4] = {vv[it].x, vv[it].y, vv[it].z, vv[it].w};
#pragma unroll
      for (int m2 = 0; m2 < 4; ++m2) {
        const int d0 = 8 * c + 2 * m2;
        const unsigned base = (unsigned)d0 * 1232 + (unsigned)pos * 2;
        *(ushort*)(smem + VTOFF + (base ^ sw))          = (ushort)(v4[m2] & 0xffffu);
        *(ushort*)(smem + VTOFF + ((base + 1232) ^ sw)) = (ushort)(v4[m2] >> 16);
      }
    }
  }
  // Vt zero pad u in [588,616) (swizzled!) — keeps phase-4 garbage out
  if (tid < 448) {
    const int d = tid / 14, jj = tid - d * 14;
    const unsigned base = (unsigned)d * 1232 + 1176u + (unsigned)jj * 4;
    *(unsigned*)(smem + VTOFF + (base ^ (((unsigned)d >> 3) << 5))) = 0u;
  }
  // rpb -> LDS
  if (tid < 845) ((float*)(smem + RPBOFF))[tid] = rv0;
  if (ri1 < 845) ((float*)(smem + RPBOFF))[ri1] = rv1;
  // LUT[u]: f = ut*169+uh*13+uw, uh, uw packed; pad entries self-invalidate
  for (int u = tid; u < 640; u += 512) {
    unsigned word;
    if (u < UPOS) {
      const int ut = (u >= 196) + (u >= 392);
      const int r2 = u - ut * 196;
      const int uh = r2 / 14;
      const int uw = r2 - uh * 14;
      const int f  = ut * 169 + uh * 13 + uw;
      word = (unsigned)f | ((unsigned)uh << 16) | ((unsigned)uw << 24);
    } else {
      word = (31u << 16) | (31u << 24);    // mh>>31 == 0 -> invalid
    }
    ((unsigned*)(smem + LUTOFF))[u] = word;
  }
  __syncthreads();

  // ---- Phase 2: QK MFMAs, raw f16 scores -> P (stride 616) ----
  {
    ushort* ph = (ushort*)(smem + POFF2);
    for (int nt = (wv >> 2); nt < 37; nt += 2) {
      const int u = nt * 16 + l16;
      const int slot = (quad + (u >> 2)) & 3;
      const bf16x8 bfrag = *(const bf16x8*)(smem + KOFF + u * 64 + slot * 16);
      f32x4 c = {0.f, 0.f, 0.f, 0.f};
      c = __builtin_amdgcn_mfma_f32_16x16x32_bf16(afrag, bfrag, c, 0, 0, 0);
#pragma unroll
      for (int r2 = 0; r2 < 4; ++r2) {
        const int qrow = mtile * 16 + quad * 4 + r2;
        ph[(size_t)qrow * 616 + u] = f2h(c[r2]);
      }
    }
  }
  __syncthreads();

  // ---- Phase 3: softmax (bias from LDS rpb, window-mask validity) ----
  {
    const int qs  = tid >> 3, l8s = tid & 7;
    const int qh_s = h0 + (qs >> 3), qw_s = w0 + (qs & 7);
    const int sh_s = min(max(qh_s - 3, 0), Hv - 7);
    const int sw_s = min(max(qw_s - 3, 0), Wv - 7);
    const int dh_s = sh_s - u_h, dw_s = sw_s - u_w;    // in [0,7]
    const unsigned mh = 0x7Fu << dh_s, mw = 0x7Fu << dw_s;
    const int Cq = rt_b * 169 + (u_h - qh_s + 6) * 13 + (u_w - qw_s + 6);
    const float* rpb_l = (const float*)(smem + RPBOFF);
    unsigned char* Prow = smem + POFF2 + (size_t)qs * 1232;
    const unsigned* LUT = (const unsigned*)(smem + LUTOFF);

    float sum = 0.f;
#pragma unroll
    for (int jc = 0; jc < 10; ++jc) {
      const int cidx = l8s + 8 * jc;
      if (cidx < 77) {
        const int u0 = cidx * 8;
        uint4 pv = *(uint4*)(Prow + cidx * 16);
        const uint4 l0 = *(const uint4*)(LUT + u0);
        const uint4 l1 = *(const uint4*)(LUT + u0 + 4);
        unsigned pw[4] = {pv.x, pv.y, pv.z, pv.w};
        const unsigned lu[8] = {l0.x, l0.y, l0.z, l0.w, l1.x, l1.y, l1.z, l1.w};
#pragma unroll
        for (int e = 0; e < 8; ++e) {
          const unsigned lut = lu[e];
          const unsigned uh = (lut >> 16) & 0xffu;
          const unsigned uw = lut >> 24;
          const bool valid = (((mh >> uh) & (mw >> uw)) & 1u) != 0u;
          int idx = (int)(lut & 0xffffu) + Cq;
          idx = min(max(idx, 0), 844);
          const float bias = rpb_l[idx];
          const unsigned short hraw =
              (e & 1) ? (unsigned short)(pw[e >> 1] >> 16)
                      : (unsigned short)(pw[e >> 1] & 0xffffu);
          float s = h2f(hraw) + bias;
          s = valid ? s : -INFINITY;     // after add: kills NaN from garbage P
          const float ex = __expf(s);
          sum += ex;
          const unsigned short ob = f2bf16(ex);
          if (e & 1) pw[e >> 1] = (pw[e >> 1] & 0x0000ffffu) | ((unsigned)ob << 16);
          else       pw[e >> 1] = (pw[e >> 1] & 0xffff0000u) | (unsigned)ob;
        }
        pv.x = pw[0]; pv.y = pw[1]; pv.z = pw[2]; pv.w = pw[3];
        *(uint4*)(Prow + cidx * 16) = pv;
      }
    }
    sum += __shfl_xor(sum, 1);
    sum += __shfl_xor(sum, 2);
    sum += __shfl_xor(sum, 4);
    if (l8s == 0) ((float*)(smem + KOFF))[qs] = 1.0f / sum;  // Ks region dead
  }
  __syncthreads();

  // ---- Phase 4: AV MFMAs + scaled store ----
  {
    const int mtA = wv >> 1, ntA = wv & 1;
    const int dcol = ntA * 16 + l16;
    const unsigned vlocal = (unsigned)dcol * 1232;
    const unsigned vsw = ((unsigned)(dcol >> 3) & 3u) << 5;
    const unsigned char* Abase = smem + POFF2 + (size_t)(mtA * 16 + l16) * 1232;
    f32x4 o = {0.f, 0.f, 0.f, 0.f};
#pragma unroll 4
    for (int kt = 0; kt < 19; ++kt) {
      const bf16x8 a  = *(const bf16x8*)(Abase + kt * 64 + quad * 16);
      const bf16x8 bb = *(const bf16x8*)(smem + VTOFF +
                          ((vlocal + kt * 64 + quad * 16) ^ vsw));
      o = __builtin_amdgcn_mfma_f32_16x16x32_bf16(a, bb, o, 0, 0, 0);
    }
    const float* invArr = (const float*)(smem + KOFF);
#pragma unroll
    for (int r2 = 0; r2 < 4; ++r2) {
      const int qrow = mtA * 16 + quad * 4 + r2;
      const float val = o[r2] * invArr[qrow];
      const int qh2 = h0 + (qrow >> 3), qw2 = w0 + (qrow & 7);
      const size_t qp2 = ((size_t)(b * Tv + t) * Hv + qh2) * Wv + qw2;
      oout[qp2 * 128 + head * 32 + dcol] = val;
    }
  }
}

// ---------------------------------------------------------------------------
extern "C" void kernel_launch(void* const* d_in, const int* in_sizes, int n_in,
                              void* d_out, int out_size, void* d_ws, size_t ws_size,
                              hipStream_t stream) {
  const float* x      = (const float*)d_in[0];
  const float* y      = (const float*)d_in[1];
  const float* qv_w   = (const float*)d_in[2];
  const float* qv_b   = (const float*)d_in[3];
  const float* k_w    = (const float*)d_in[4];
  const float* k_b    = (const float*)d_in[5];
  const float* proj_w = (const float*)d_in[6];
  const float* proj_b = (const float*)d_in[7];
  const float* rpb    = (const float*)d_in[8];
  float* out = (float*)d_out;

  const size_t elems = (size_t)MPOS * 128;        // 8,388,608
  ushort* qbuf = (ushort*)d_ws;                   // 16.8 MB (bf16, SCALE folded)
  ushort* kbuf = qbuf + elems;                    // 16.8 MB
  ushort* vbuf = kbuf + elems;                    // 16.8 MB
  float*  obuf = (float*)(vbuf + elems);          // 33.5 MB (attn out fp32)
  ushort* wqvT   = (ushort*)(obuf + elems);
  ushort* wkT    = wqvT + 256 * KPAD;
  ushort* wpT_hi = wkT + 128 * KPAD;
  ushort* wpT_lo = wpT_hi + 128 * KPAD;

  preconvert    <<<256,  256, 0, stream>>>(qv_w, k_w, proj_w, wqvT, wkT, wpT_hi, wpT_lo);
  gemm_qv_mfma  <<<512,  512, 0, stream>>>(x, wqvT, qv_b, qbuf, vbuf);
  gemm_k_mfma   <<<512,  512, 0, stream>>>(y, wkT, k_b, kbuf);
  na3d_tile     <<<4096, 512, 0, stream>>>(qbuf, kbuf, vbuf, rpb, obuf);
  gemm_proj_mfma<<<512,  512, 0, stream>>>(obuf, wpT_hi, wpT_lo, proj_b, out);
}

// Round 2
// 327.376 us; speedup vs baseline: 1.1558x; 1.0377x over previous
//
#include <hip/hip_runtime.h>
#include <hip/hip_bf16.h>
#include <hip/hip_fp16.h>
#include <cmath>

// Problem constants
#define Bv   2
#define Tv   8
#define Hv   64
#define Wv   64
#define MPOS (Bv*Tv*Hv*Wv)           // 65536 positions
#define SCALEv 0.17677669529663687f  // 32^-0.5

// Attention tiling: 8x8 queries (one t, one b, one head) per block.
#define U_H   14
#define U_W   14
#define UPOS  588                    // 3*14*14 union K/V positions

// Attention LDS layout (bytes). See R1/R2 comments.
#define KOFF   0                     // K: 592 slots x 64 B (linear dest, src-swizzled)
#define VTOFF  37888                 // Vt: 32 x 1232 B, XOR-swizzled by (d>>3)<<5
#define POFF2  77312                 // P : 64 x 1232 B (616 f16 -> bf16 in place)
#define LUTOFF 156160                // 640 x 4 B
#define RPBOFF 158720                // 845 f32 (this head's rpb)
#define SMEM_BYTES 162112            // <= 163840 -> 1 block/CU (16 waves = 4/SIMD)

// GEMM LDS row padding: 136 bf16 = 272 B; 272/4 = 68 dwords == 4 (mod 32)
#define KPAD 136

typedef __attribute__((ext_vector_type(8))) short bf16x8;   // MFMA A/B frag
typedef __attribute__((ext_vector_type(4))) float f32x4;    // MFMA C/D frag

__device__ __forceinline__ unsigned short f2bf16(float x) {
  return __builtin_bit_cast(unsigned short, __float2bfloat16(x));
}
__device__ __forceinline__ float bf2f(unsigned short h) {
  return __uint_as_float((unsigned)h << 16);
}
__device__ __forceinline__ float h2f(unsigned short h) {
  return __half2float(__builtin_bit_cast(__half, h));
}
__device__ __forceinline__ unsigned short f2h(float x) {
  return __builtin_bit_cast(unsigned short, __float2half(x));
}
__device__ __forceinline__ unsigned pk2(float a, float b) {
  return (unsigned)f2bf16(a) | ((unsigned)f2bf16(b) << 16);
}
// async global->LDS, 16B per lane; dest = wave-uniform base + lane*16
__device__ __forceinline__ void gload_lds16(const void* gsrc, void* ldst) {
  __builtin_amdgcn_global_load_lds(
      (const __attribute__((address_space(1))) unsigned int*)gsrc,
      (__attribute__((address_space(3))) unsigned int*)ldst, 16, 0, 0);
}

// ---------------------------------------------------------------------------
// Preconvert weights: transpose to [n][k] bf16 with KPAD row stride.
// proj_w additionally split hi/lo for the bf16x3 fp32-accurate GEMM.
// ---------------------------------------------------------------------------
__global__ __launch_bounds__(256) void preconvert(
    const float* __restrict__ qv_w, const float* __restrict__ k_w,
    const float* __restrict__ proj_w,
    ushort* __restrict__ wqvT, ushort* __restrict__ wkT,
    ushort* __restrict__ wpT_hi, ushort* __restrict__ wpT_lo) {
  const int id = blockIdx.x * 256 + threadIdx.x;
  if (id < 32768) {                       // qv: n<256, k<128
    const int n = id >> 7, kk = id & 127;
    wqvT[n * KPAD + kk] = f2bf16(qv_w[kk * 256 + n]);
  } else if (id < 49152) {                // k: n<128
    const int j = id - 32768;
    const int n = j >> 7, kk = j & 127;
    wkT[n * KPAD + kk] = f2bf16(k_w[kk * 128 + n]);
  } else {                                // proj: hi/lo split
    const int j = id - 49152;
    const int n = j >> 7, kk = j & 127;
    const float v = proj_w[kk * 128 + n];
    const unsigned short hi = f2bf16(v);
    wpT_hi[n * KPAD + kk] = hi;
    wpT_lo[n * KPAD + kk] = f2bf16(v - bf2f(hi));
  }
}

// ---------------------------------------------------------------------------
// Fused q/v/k projection GEMMs. Grid 1536 x 512thr; seg = bx>>9 (0=q,1=v,2=k).
// Each block: 128 rows x 128 cols. A-frags loaded DIRECTLY global->reg (each
// element consumed by exactly one lane -> no LDS staging). W via gload_lds.
// 35 KB LDS -> up to 4 blocks/CU.
// ---------------------------------------------------------------------------
__global__ __launch_bounds__(512) void gemm_qvk(
    const float* __restrict__ x, const float* __restrict__ y,
    const ushort* __restrict__ wqvT, const ushort* __restrict__ wkT,
    const float* __restrict__ qv_b, const float* __restrict__ k_b,
    ushort* __restrict__ qbuf, ushort* __restrict__ vbuf,
    ushort* __restrict__ kbuf) {
  __shared__ ushort Ws[128 * KPAD];
  const int tid  = threadIdx.x;
  const int bx   = blockIdx.x;
  const int seg  = bx >> 9;                 // 0=q, 1=v, 2=k
  const int row0 = (bx & 511) * 128;

  const float*  A    = (seg == 2) ? y : x;
  const ushort* W    = (seg == 0) ? wqvT : (seg == 1) ? wqvT + 128 * KPAD : wkT;
  const float*  bias = (seg == 0) ? qv_b : (seg == 1) ? qv_b + 128 : k_b;
  ushort*       outp = (seg == 0) ? qbuf : (seg == 1) ? vbuf : kbuf;
  const float   scale = (seg == 0) ? SCALEv : 1.0f;

  // stage W async: 2176 uint4
  {
    const uint4* wg = (const uint4*)W;
    for (int i = tid; i < 2176; i += 512)
      gload_lds16(wg + i, (uint4*)Ws + i);
  }

  const int wv = tid >> 6, lane = tid & 63, quad = lane >> 4, l16 = lane & 15;
  const int arow = row0 + wv * 16 + l16;

  // A-frags direct to regs: 4 x 32B contiguous per lane
  bf16x8 af[4];
#pragma unroll
  for (int kk = 0; kk < 4; ++kk) {
    const float4* ap = (const float4*)(A + (size_t)arow * 128 + kk * 32 + quad * 8);
    const float4 a = ap[0], b2 = ap[1];
    af[kk] = __builtin_bit_cast(bf16x8,
        make_uint4(pk2(a.x, a.y), pk2(a.z, a.w), pk2(b2.x, b2.y), pk2(b2.z, b2.w)));
  }
  __syncthreads();

  f32x4 C[8];
#pragma unroll
  for (int nt = 0; nt < 8; ++nt) C[nt] = (f32x4){0.f, 0.f, 0.f, 0.f};

#pragma unroll
  for (int kk = 0; kk < 4; ++kk) {
#pragma unroll
    for (int nt = 0; nt < 8; ++nt) {
      const bf16x8 b2 = *(const bf16x8*)(Ws + (nt * 16 + l16) * KPAD + kk * 32 + quad * 8);
      C[nt] = __builtin_amdgcn_mfma_f32_16x16x32_bf16(af[kk], b2, C[nt], 0, 0, 0);
    }
  }

#pragma unroll
  for (int nt = 0; nt < 8; ++nt) {
    const int col = nt * 16 + l16;
    const float bv = bias[col];
#pragma unroll
    for (int r2 = 0; r2 < 4; ++r2) {
      const size_t row = row0 + wv * 16 + quad * 4 + r2;
      outp[row * 128 + col] = f2bf16((C[nt][r2] + bv) * scale);
    }
  }
}

// ---------------------------------------------------------------------------
// Output projection, bf16x3 (fp32-accurate). A hi/lo built in regs (no LDS);
// W hi/lo via gload_lds. 70 KB LDS -> 2 blocks/CU.
// ---------------------------------------------------------------------------
__global__ __launch_bounds__(512) void gemm_proj_mfma(
    const float* __restrict__ o, const ushort* __restrict__ wpT_hi,
    const ushort* __restrict__ wpT_lo, const float* __restrict__ proj_b,
    float* __restrict__ out) {
  __shared__ ushort Wh[128 * KPAD];
  __shared__ ushort Wl[128 * KPAD];
  const int tid  = threadIdx.x;
  const int row0 = blockIdx.x * 128;
  {
    const uint4* wgh = (const uint4*)wpT_hi;
    const uint4* wgl = (const uint4*)wpT_lo;
    for (int i = tid; i < 2176; i += 512) {
      gload_lds16(wgh + i, (uint4*)Wh + i);
      gload_lds16(wgl + i, (uint4*)Wl + i);
    }
  }

  const int wv = tid >> 6, lane = tid & 63, quad = lane >> 4, l16 = lane & 15;
  const int arow = row0 + wv * 16 + l16;

  bf16x8 ah[4], al[4];
#pragma unroll
  for (int kk = 0; kk < 4; ++kk) {
    const float4* ap = (const float4*)(o + (size_t)arow * 128 + kk * 32 + quad * 8);
    const float4 a = ap[0], b2 = ap[1];
    const float vs[8] = {a.x, a.y, a.z, a.w, b2.x, b2.y, b2.z, b2.w};
    unsigned hw[4], lw[4];
#pragma unroll
    for (int e = 0; e < 4; ++e) {
      const unsigned short h0 = f2bf16(vs[2 * e]);
      const unsigned short h1 = f2bf16(vs[2 * e + 1]);
      hw[e] = (unsigned)h0 | ((unsigned)h1 << 16);
      lw[e] = (unsigned)f2bf16(vs[2 * e] - bf2f(h0)) |
              ((unsigned)f2bf16(vs[2 * e + 1] - bf2f(h1)) << 16);
    }
    ah[kk] = __builtin_bit_cast(bf16x8, make_uint4(hw[0], hw[1], hw[2], hw[3]));
    al[kk] = __builtin_bit_cast(bf16x8, make_uint4(lw[0], lw[1], lw[2], lw[3]));
  }
  __syncthreads();

  f32x4 C[8];
#pragma unroll
  for (int nt = 0; nt < 8; ++nt) C[nt] = (f32x4){0.f, 0.f, 0.f, 0.f};

#pragma unroll
  for (int kk = 0; kk < 4; ++kk) {
#pragma unroll
    for (int nt = 0; nt < 8; ++nt) {
      const int boff = (nt * 16 + l16) * KPAD + kk * 32 + quad * 8;
      const bf16x8 bh = *(const bf16x8*)(Wh + boff);
      const bf16x8 bl = *(const bf16x8*)(Wl + boff);
      C[nt] = __builtin_amdgcn_mfma_f32_16x16x32_bf16(ah[kk], bh, C[nt], 0, 0, 0);
      C[nt] = __builtin_amdgcn_mfma_f32_16x16x32_bf16(ah[kk], bl, C[nt], 0, 0, 0);
      C[nt] = __builtin_amdgcn_mfma_f32_16x16x32_bf16(al[kk], bh, C[nt], 0, 0, 0);
    }
  }

#pragma unroll
  for (int nt = 0; nt < 8; ++nt) {
    const int col = nt * 16 + l16;
    const float bv = proj_b[col];
#pragma unroll
    for (int r2 = 0; r2 < 4; ++r2) {
      const size_t row = row0 + wv * 16 + quad * 4 + r2;
      out[row * 128 + col] = C[nt][r2] + bv;
    }
  }
}

// ---------------------------------------------------------------------------
// MFMA NA3D attention (union-GEMM). Block = 8x8 query tile (one b,t,head).
// NOW 1024 threads = 16 waves (4 waves/SIMD at 1 block/CU) — same LDS, work
// re-partitioned for 2x occupancy.
// ---------------------------------------------------------------------------
__global__ __launch_bounds__(1024, 1)
void na3d_tile(
    const ushort* __restrict__ qin,
    const ushort* __restrict__ kin,
    const ushort* __restrict__ vin,
    const float* __restrict__ rpb,
    float* __restrict__ oout) {
  __shared__ __align__(16) unsigned char smem[SMEM_BYTES];

  const int tid  = threadIdx.x;
  const int wv   = tid >> 6;          // 0..15
  const int lane = tid & 63;
  const int quad = lane >> 4;
  const int l16  = lane & 15;

  const int bx   = blockIdx.x;
  const int head = bx & 3;
  const int tile = bx >> 2;
  const int w0 = (tile & 7) << 3;
  const int h0 = ((tile >> 3) & 7) << 3;
  const int t  = (tile >> 6) & 7;
  const int b  = tile >> 9;

  const int st  = min(max(t - 1, 0), Tv - 3);
  const int u_h = min(max(h0 - 3, 0), Hv - U_H);
  const int u_w = min(max(w0 - 3, 0), Wv - U_W);
  const int rt_b = st - t + 2;   // 0..2

  // ---- Phase 1 ----
  // A-frag early (plain load, waits before first MFMA)
  const int mtile = wv & 3;
  bf16x8 afrag;
  {
    const int q_a  = mtile * 16 + l16;
    const int qh_a = h0 + (q_a >> 3), qw_a = w0 + (q_a & 7);
    const size_t qpos_a = ((size_t)(b * Tv + t) * Hv + qh_a) * Wv + qw_a;
    afrag = *(const bf16x8*)(qin + qpos_a * 128 + head * 32 + quad * 8);
  }

  // rpb -> reg (issue early), write to LDS later
  float rv0 = 0.f;
  if (tid < 845) rv0 = rpb[head * 845 + tid];

  // V: issue all loads per thread up front (one latency window)
  uint4 vv[3];
#pragma unroll
  for (int it = 0; it < 3; ++it) {
    const int j = tid + it * 1024;         // [0, 2352)
    if (j < UPOS * 4) {
      const int pos = j >> 2, c = j & 3;
      const int ta = pos / 196;
      const int r  = pos - ta * 196;
      const int rh = r / 14;
      const int ha = u_h + rh;
      const int wa = u_w + (r - rh * 14);
      const size_t gpos = (((size_t)(b * Tv + st + ta) * Hv + ha) * Wv + wa);
      vv[it] = ((const uint4*)vin)[gpos * 16 + head * 4 + c];
    }
  }

  // K: async global->LDS, source pre-swizzled so the LDS dest is linear.
  for (int ch = wv; ch < 37; ch += 16) {
    const int m = ch * 64 + lane;          // [0, 2368)
    int pos = m >> 2;
    const int slot = m & 3;
    if (pos > UPOS - 1) pos = UPOS - 1;    // dup-load; garbage masked later
    const int c  = (slot - (pos >> 2)) & 3;
    const int ta = pos / 196;
    const int r  = pos - ta * 196;
    const int rh = r / 14;
    const int ha = u_h + rh;
    const int wa = u_w + (r - rh * 14);
    const size_t gpos = (((size_t)(b * Tv + st + ta) * Hv + ha) * Wv + wa);
    gload_lds16((const uint4*)kin + gpos * 16 + head * 4 + c,
                smem + KOFF + ch * 1024 + lane * 16);
  }

  // V repack -> Vt, XOR-swizzled by (d>>3)<<5
#pragma unroll
  for (int it = 0; it < 3; ++it) {
    const int j = tid + it * 1024;
    if (j < UPOS * 4) {
      const int pos = j >> 2, c = j & 3;
      const unsigned sw = (unsigned)c << 5;          // d>>3 == c for this chunk
      const unsigned v4[4] = {vv[it].x, vv[it].y, vv[it].z, vv[it].w};
#pragma unroll
      for (int m2 = 0; m2 < 4; ++m2) {
        const int d0 = 8 * c + 2 * m2;
        const unsigned base = (unsigned)d0 * 1232 + (unsigned)pos * 2;
        *(ushort*)(smem + VTOFF + (base ^ sw))          = (ushort)(v4[m2] & 0xffffu);
        *(ushort*)(smem + VTOFF + ((base + 1232) ^ sw)) = (ushort)(v4[m2] >> 16);
      }
    }
  }
  // Vt zero pad u in [588,616) (swizzled!)
  if (tid < 448) {
    const int d = tid / 14, jj = tid - d * 14;
    const unsigned base = (unsigned)d * 1232 + 1176u + (unsigned)jj * 4;
    *(unsigned*)(smem + VTOFF + (base ^ (((unsigned)d >> 3) << 5))) = 0u;
  }
  // rpb -> LDS
  if (tid < 845) ((float*)(smem + RPBOFF))[tid] = rv0;
  // LUT[u]: pad entries self-invalidate
  if (tid < 640) {
    const int u = tid;
    unsigned word;
    if (u < UPOS) {
      const int ut = (u >= 196) + (u >= 392);
      const int r2 = u - ut * 196;
      const int uh = r2 / 14;
      const int uw = r2 - uh * 14;
      const int f  = ut * 169 + uh * 13 + uw;
      word = (unsigned)f | ((unsigned)uh << 16) | ((unsigned)uw << 24);
    } else {
      word = (31u << 16) | (31u << 24);
    }
    ((unsigned*)(smem + LUTOFF))[u] = word;
  }
  __syncthreads();

  // ---- Phase 2: QK MFMAs, raw f16 scores -> P ----
  {
    ushort* ph = (ushort*)(smem + POFF2);
    for (int nt = (wv >> 2); nt < 37; nt += 4) {
      const int u = nt * 16 + l16;
      const int slot = (quad + (u >> 2)) & 3;
      const bf16x8 bfrag = *(const bf16x8*)(smem + KOFF + u * 64 + slot * 16);
      f32x4 c = {0.f, 0.f, 0.f, 0.f};
      c = __builtin_amdgcn_mfma_f32_16x16x32_bf16(afrag, bfrag, c, 0, 0, 0);
#pragma unroll
      for (int r2 = 0; r2 < 4; ++r2) {
        const int qrow = mtile * 16 + quad * 4 + r2;
        ph[(size_t)qrow * 616 + u] = f2h(c[r2]);
      }
    }
  }
  __syncthreads();

  // ---- Phase 3: softmax (16 threads/row) ----
  {
    const int qs = tid >> 4, l16s = tid & 15;
    const int qh_s = h0 + (qs >> 3), qw_s = w0 + (qs & 7);
    const int sh_s = min(max(qh_s - 3, 0), Hv - 7);
    const int sw_s = min(max(qw_s - 3, 0), Wv - 7);
    const int dh_s = sh_s - u_h, dw_s = sw_s - u_w;    // in [0,7]
    const unsigned mh = 0x7Fu << dh_s, mw = 0x7Fu << dw_s;
    const int Cq = rt_b * 169 + (u_h - qh_s + 6) * 13 + (u_w - qw_s + 6);
    const float* rpb_l = (const float*)(smem + RPBOFF);
    unsigned char* Prow = smem + POFF2 + (size_t)qs * 1232;
    const unsigned* LUT = (const unsigned*)(smem + LUTOFF);

    float sum = 0.f;
#pragma unroll
    for (int jc = 0; jc < 5; ++jc) {
      const int cidx = l16s + 16 * jc;
      if (cidx < 77) {
        const int u0 = cidx * 8;
        uint4 pv = *(uint4*)(Prow + cidx * 16);
        const uint4 l0 = *(const uint4*)(LUT + u0);
        const uint4 l1 = *(const uint4*)(LUT + u0 + 4);
        unsigned pw[4] = {pv.x, pv.y, pv.z, pv.w};
        const unsigned lu[8] = {l0.x, l0.y, l0.z, l0.w, l1.x, l1.y, l1.z, l1.w};
#pragma unroll
        for (int e = 0; e < 8; ++e) {
          const unsigned lut = lu[e];
          const unsigned uh = (lut >> 16) & 0xffu;
          const unsigned uw = lut >> 24;
          const bool valid = (((mh >> uh) & (mw >> uw)) & 1u) != 0u;
          int idx = (int)(lut & 0xffffu) + Cq;
          idx = min(max(idx, 0), 844);
          const float bias = rpb_l[idx];
          const unsigned short hraw =
              (e & 1) ? (unsigned short)(pw[e >> 1] >> 16)
                      : (unsigned short)(pw[e >> 1] & 0xffffu);
          float s = h2f(hraw) + bias;
          s = valid ? s : -INFINITY;
          const float ex = __expf(s);
          sum += ex;
          const unsigned short ob = f2bf16(ex);
          if (e & 1) pw[e >> 1] = (pw[e >> 1] & 0x0000ffffu) | ((unsigned)ob << 16);
          else       pw[e >> 1] = (pw[e >> 1] & 0xffff0000u) | (unsigned)ob;
        }
        pv.x = pw[0]; pv.y = pw[1]; pv.z = pw[2]; pv.w = pw[3];
        *(uint4*)(Prow + cidx * 16) = pv;
      }
    }
    sum += __shfl_xor(sum, 1);
    sum += __shfl_xor(sum, 2);
    sum += __shfl_xor(sum, 4);
    sum += __shfl_xor(sum, 8);
    if (l16s == 0) ((float*)(smem + KOFF))[qs] = 1.0f / sum;  // K region dead
  }
  __syncthreads();

  // ---- Phase 4: AV MFMAs, kt-split across wave halves + LDS combine ----
  {
    const int khalf = wv >> 3;            // 0: kt 0..9, 1: kt 10..18
    const int mtA = (wv >> 1) & 3;
    const int ntA = wv & 1;
    const int dcol = ntA * 16 + l16;
    const unsigned vlocal = (unsigned)dcol * 1232;
    const unsigned vsw = ((unsigned)(dcol >> 3) & 3u) << 5;
    const unsigned char* Abase = smem + POFF2 + (size_t)(mtA * 16 + l16) * 1232;
    f32x4 o = {0.f, 0.f, 0.f, 0.f};
    const int kt0 = khalf ? 10 : 0;
    const int kt1 = khalf ? 19 : 10;
#pragma unroll 4
    for (int kt = kt0; kt < kt1; ++kt) {
      const bf16x8 a  = *(const bf16x8*)(Abase + kt * 64 + quad * 16);
      const bf16x8 bb = *(const bf16x8*)(smem + VTOFF +
                          ((vlocal + kt * 64 + quad * 16) ^ vsw));
      o = __builtin_amdgcn_mfma_f32_16x16x32_bf16(a, bb, o, 0, 0, 0);
    }
    f32x4* part = (f32x4*)(smem + KOFF + 1024);   // 8 KB scratch in dead K region
    if (khalf) part[(wv & 7) * 64 + lane] = o;
    __syncthreads();
    if (!khalf) {
      const f32x4 p2 = part[wv * 64 + lane];
      const float* invArr = (const float*)(smem + KOFF);
#pragma unroll
      for (int r2 = 0; r2 < 4; ++r2) {
        const int qrow = mtA * 16 + quad * 4 + r2;
        const float val = (o[r2] + p2[r2]) * invArr[qrow];
        const int qh2 = h0 + (qrow >> 3), qw2 = w0 + (qrow & 7);
        const size_t qp2 = ((size_t)(b * Tv + t) * Hv + qh2) * Wv + qw2;
        oout[qp2 * 128 + head * 32 + dcol] = val;
      }
    }
  }
}

// ---------------------------------------------------------------------------
extern "C" void kernel_launch(void* const* d_in, const int* in_sizes, int n_in,
                              void* d_out, int out_size, void* d_ws, size_t ws_size,
                              hipStream_t stream) {
  const float* x      = (const float*)d_in[0];
  const float* y      = (const float*)d_in[1];
  const float* qv_w   = (const float*)d_in[2];
  const float* qv_b   = (const float*)d_in[3];
  const float* k_w    = (const float*)d_in[4];
  const float* k_b    = (const float*)d_in[5];
  const float* proj_w = (const float*)d_in[6];
  const float* proj_b = (const float*)d_in[7];
  const float* rpb    = (const float*)d_in[8];
  float* out = (float*)d_out;

  const size_t elems = (size_t)MPOS * 128;        // 8,388,608
  ushort* qbuf = (ushort*)d_ws;                   // 16.8 MB (bf16, SCALE folded)
  ushort* kbuf = qbuf + elems;                    // 16.8 MB
  ushort* vbuf = kbuf + elems;                    // 16.8 MB
  float*  obuf = (float*)(vbuf + elems);          // 33.5 MB (attn out fp32)
  ushort* wqvT   = (ushort*)(obuf + elems);
  ushort* wkT    = wqvT + 256 * KPAD;
  ushort* wpT_hi = wkT + 128 * KPAD;
  ushort* wpT_lo = wpT_hi + 128 * KPAD;

  preconvert    <<<256,  256, 0, stream>>>(qv_w, k_w, proj_w, wqvT, wkT, wpT_hi, wpT_lo);
  gemm_qvk      <<<1536, 512, 0, stream>>>(x, y, wqvT, wkT, qv_b, k_b, qbuf, vbuf, kbuf);
  na3d_tile     <<<4096, 1024, 0, stream>>>(qbuf, kbuf, vbuf, rpb, obuf);
  gemm_proj_mfma<<<512,  512, 0, stream>>>(obuf, wpT_hi, wpT_lo, proj_b, out);
}

// Round 3
// 284.403 us; speedup vs baseline: 1.3305x; 1.1511x over previous
//
#include <hip/hip_runtime.h>
#include <hip/hip_bf16.h>
#include <hip/hip_fp16.h>
#include <cmath>

// Problem constants
#define Bv   2
#define Tv   8
#define Hv   64
#define Wv   64
#define MPOS (Bv*Tv*Hv*Wv)           // 65536 positions
#define SCALEv 0.17677669529663687f  // 32^-0.5

// Attention tiling: 8x8 queries (one t, one b, one head) per block.
#define U_H   14
#define U_W   14
#define UPOS  588                    // 3*14*14 union K/V positions

// Attention LDS layout (bytes).
#define KOFF   0                     // K: 592 slots x 64 B (linear dest, src-swizzled)
#define VTOFF  37888                 // Vt: 32 x 1232 B, XOR-swizzled by (d>>3)<<5
#define POFF2  77312                 // P : 64 x 1232 B (616 f16 -> bf16 in place)
#define RPBOFF 158720                // 845 f32 (this head's rpb)
#define SMEM_BYTES 162112            // <= 163840 -> 1 block/CU (16 waves = 4/SIMD)

// GEMM LDS row padding: 136 bf16 = 272 B; 272/4 = 68 dwords == 4 (mod 32)
#define KPAD 136

typedef __attribute__((ext_vector_type(8))) short bf16x8;   // MFMA A/B frag
typedef __attribute__((ext_vector_type(4))) float f32x4;    // MFMA C/D frag

__device__ __forceinline__ unsigned short f2bf16(float x) {
  return __builtin_bit_cast(unsigned short, __float2bfloat16(x));
}
__device__ __forceinline__ float bf2f(unsigned short h) {
  return __uint_as_float((unsigned)h << 16);
}
__device__ __forceinline__ float h2f(unsigned short h) {
  return __half2float(__builtin_bit_cast(__half, h));
}
__device__ __forceinline__ unsigned short f2h(float x) {
  return __builtin_bit_cast(unsigned short, __float2half(x));
}
__device__ __forceinline__ unsigned pk2(float a, float b) {
  return (unsigned)f2bf16(a) | ((unsigned)f2bf16(b) << 16);
}
// async global->LDS, 16B per lane; dest = wave-uniform base + lane*16
__device__ __forceinline__ void gload_lds16(const void* gsrc, void* ldst) {
  __builtin_amdgcn_global_load_lds(
      (const __attribute__((address_space(1))) unsigned int*)gsrc,
      (__attribute__((address_space(3))) unsigned int*)ldst, 16, 0, 0);
}

// ---------------------------------------------------------------------------
// Preconvert weights: transpose to [n][k] bf16 with KPAD row stride.
// proj_w additionally split hi/lo for the bf16x3 fp32-accurate GEMM.
// ---------------------------------------------------------------------------
__global__ __launch_bounds__(256) void preconvert(
    const float* __restrict__ qv_w, const float* __restrict__ k_w,
    const float* __restrict__ proj_w,
    ushort* __restrict__ wqvT, ushort* __restrict__ wkT,
    ushort* __restrict__ wpT_hi, ushort* __restrict__ wpT_lo) {
  const int id = blockIdx.x * 256 + threadIdx.x;
  if (id < 32768) {                       // qv: n<256, k<128
    const int n = id >> 7, kk = id & 127;
    wqvT[n * KPAD + kk] = f2bf16(qv_w[kk * 256 + n]);
  } else if (id < 49152) {                // k: n<128
    const int j = id - 32768;
    const int n = j >> 7, kk = j & 127;
    wkT[n * KPAD + kk] = f2bf16(k_w[kk * 128 + n]);
  } else {                                // proj: hi/lo split
    const int j = id - 49152;
    const int n = j >> 7, kk = j & 127;
    const float v = proj_w[kk * 128 + n];
    const unsigned short hi = f2bf16(v);
    wpT_hi[n * KPAD + kk] = hi;
    wpT_lo[n * KPAD + kk] = f2bf16(v - bf2f(hi));
  }
}

// ---------------------------------------------------------------------------
// Fused q/v/k projection GEMMs. Grid 1536 x 512thr; seg = bx>>9 (0=q,1=v,2=k).
// Each block: 128 rows x 128 cols. A-frags loaded DIRECTLY global->reg.
// ---------------------------------------------------------------------------
__global__ __launch_bounds__(512) void gemm_qvk(
    const float* __restrict__ x, const float* __restrict__ y,
    const ushort* __restrict__ wqvT, const ushort* __restrict__ wkT,
    const float* __restrict__ qv_b, const float* __restrict__ k_b,
    ushort* __restrict__ qbuf, ushort* __restrict__ vbuf,
    ushort* __restrict__ kbuf) {
  __shared__ ushort Ws[128 * KPAD];
  const int tid  = threadIdx.x;
  const int bx   = blockIdx.x;
  const int seg  = bx >> 9;                 // 0=q, 1=v, 2=k
  const int row0 = (bx & 511) * 128;

  const float*  A    = (seg == 2) ? y : x;
  const ushort* W    = (seg == 0) ? wqvT : (seg == 1) ? wqvT + 128 * KPAD : wkT;
  const float*  bias = (seg == 0) ? qv_b : (seg == 1) ? qv_b + 128 : k_b;
  ushort*       outp = (seg == 0) ? qbuf : (seg == 1) ? vbuf : kbuf;
  const float   scale = (seg == 0) ? SCALEv : 1.0f;

  // stage W async: 2176 uint4
  {
    const uint4* wg = (const uint4*)W;
    for (int i = tid; i < 2176; i += 512)
      gload_lds16(wg + i, (uint4*)Ws + i);
  }

  const int wv = tid >> 6, lane = tid & 63, quad = lane >> 4, l16 = lane & 15;
  const int arow = row0 + wv * 16 + l16;

  // A-frags direct to regs: 4 x 32B contiguous per lane
  bf16x8 af[4];
#pragma unroll
  for (int kk = 0; kk < 4; ++kk) {
    const float4* ap = (const float4*)(A + (size_t)arow * 128 + kk * 32 + quad * 8);
    const float4 a = ap[0], b2 = ap[1];
    af[kk] = __builtin_bit_cast(bf16x8,
        make_uint4(pk2(a.x, a.y), pk2(a.z, a.w), pk2(b2.x, b2.y), pk2(b2.z, b2.w)));
  }
  __syncthreads();

  f32x4 C[8];
#pragma unroll
  for (int nt = 0; nt < 8; ++nt) C[nt] = (f32x4){0.f, 0.f, 0.f, 0.f};

#pragma unroll
  for (int kk = 0; kk < 4; ++kk) {
#pragma unroll
    for (int nt = 0; nt < 8; ++nt) {
      const bf16x8 b2 = *(const bf16x8*)(Ws + (nt * 16 + l16) * KPAD + kk * 32 + quad * 8);
      C[nt] = __builtin_amdgcn_mfma_f32_16x16x32_bf16(af[kk], b2, C[nt], 0, 0, 0);
    }
  }

#pragma unroll
  for (int nt = 0; nt < 8; ++nt) {
    const int col = nt * 16 + l16;
    const float bv = bias[col];
#pragma unroll
    for (int r2 = 0; r2 < 4; ++r2) {
      const size_t row = row0 + wv * 16 + quad * 4 + r2;
      outp[row * 128 + col] = f2bf16((C[nt][r2] + bv) * scale);
    }
  }
}

// ---------------------------------------------------------------------------
// Output projection, bf16x3 (fp32-accurate). A hi/lo built in regs (no LDS);
// W hi/lo via gload_lds. 70 KB LDS -> 2 blocks/CU.
// ---------------------------------------------------------------------------
__global__ __launch_bounds__(512) void gemm_proj_mfma(
    const float* __restrict__ o, const ushort* __restrict__ wpT_hi,
    const ushort* __restrict__ wpT_lo, const float* __restrict__ proj_b,
    float* __restrict__ out) {
  __shared__ ushort Wh[128 * KPAD];
  __shared__ ushort Wl[128 * KPAD];
  const int tid  = threadIdx.x;
  const int row0 = blockIdx.x * 128;
  {
    const uint4* wgh = (const uint4*)wpT_hi;
    const uint4* wgl = (const uint4*)wpT_lo;
    for (int i = tid; i < 2176; i += 512) {
      gload_lds16(wgh + i, (uint4*)Wh + i);
      gload_lds16(wgl + i, (uint4*)Wl + i);
    }
  }

  const int wv = tid >> 6, lane = tid & 63, quad = lane >> 4, l16 = lane & 15;
  const int arow = row0 + wv * 16 + l16;

  bf16x8 ah[4], al[4];
#pragma unroll
  for (int kk = 0; kk < 4; ++kk) {
    const float4* ap = (const float4*)(o + (size_t)arow * 128 + kk * 32 + quad * 8);
    const float4 a = ap[0], b2 = ap[1];
    const float vs[8] = {a.x, a.y, a.z, a.w, b2.x, b2.y, b2.z, b2.w};
    unsigned hw[4], lw[4];
#pragma unroll
    for (int e = 0; e < 4; ++e) {
      const unsigned short h0 = f2bf16(vs[2 * e]);
      const unsigned short h1 = f2bf16(vs[2 * e + 1]);
      hw[e] = (unsigned)h0 | ((unsigned)h1 << 16);
      lw[e] = (unsigned)f2bf16(vs[2 * e] - bf2f(h0)) |
              ((unsigned)f2bf16(vs[2 * e + 1] - bf2f(h1)) << 16);
    }
    ah[kk] = __builtin_bit_cast(bf16x8, make_uint4(hw[0], hw[1], hw[2], hw[3]));
    al[kk] = __builtin_bit_cast(bf16x8, make_uint4(lw[0], lw[1], lw[2], lw[3]));
  }
  __syncthreads();

  f32x4 C[8];
#pragma unroll
  for (int nt = 0; nt < 8; ++nt) C[nt] = (f32x4){0.f, 0.f, 0.f, 0.f};

#pragma unroll
  for (int kk = 0; kk < 4; ++kk) {
#pragma unroll
    for (int nt = 0; nt < 8; ++nt) {
      const int boff = (nt * 16 + l16) * KPAD + kk * 32 + quad * 8;
      const bf16x8 bh = *(const bf16x8*)(Wh + boff);
      const bf16x8 bl = *(const bf16x8*)(Wl + boff);
      C[nt] = __builtin_amdgcn_mfma_f32_16x16x32_bf16(ah[kk], bh, C[nt], 0, 0, 0);
      C[nt] = __builtin_amdgcn_mfma_f32_16x16x32_bf16(ah[kk], bl, C[nt], 0, 0, 0);
      C[nt] = __builtin_amdgcn_mfma_f32_16x16x32_bf16(al[kk], bh, C[nt], 0, 0, 0);
    }
  }

#pragma unroll
  for (int nt = 0; nt < 8; ++nt) {
    const int col = nt * 16 + l16;
    const float bv = proj_b[col];
#pragma unroll
    for (int r2 = 0; r2 < 4; ++r2) {
      const size_t row = row0 + wv * 16 + quad * 4 + r2;
      out[row * 128 + col] = C[nt][r2] + bv;
    }
  }
}

// ---------------------------------------------------------------------------
// MFMA NA3D attention (union-GEMM). Block = 8x8 query tile (one b,t,head).
// 1024 threads = 16 waves. R3: windowed softmax — only the 147 valid
// neighbors per query get bias+exp (was 616 with mask); P zeroed wholesale.
// ---------------------------------------------------------------------------
__global__ __launch_bounds__(1024, 1)
void na3d_tile(
    const ushort* __restrict__ qin,
    const ushort* __restrict__ kin,
    const ushort* __restrict__ vin,
    const float* __restrict__ rpb,
    float* __restrict__ oout) {
  __shared__ __align__(16) unsigned char smem[SMEM_BYTES];

  const int tid  = threadIdx.x;
  const int wv   = tid >> 6;          // 0..15
  const int lane = tid & 63;
  const int quad = lane >> 4;
  const int l16  = lane & 15;

  const int bx   = blockIdx.x;
  const int head = bx & 3;
  const int tile = bx >> 2;
  const int w0 = (tile & 7) << 3;
  const int h0 = ((tile >> 3) & 7) << 3;
  const int t  = (tile >> 6) & 7;
  const int b  = tile >> 9;

  const int st  = min(max(t - 1, 0), Tv - 3);
  const int u_h = min(max(h0 - 3, 0), Hv - U_H);
  const int u_w = min(max(w0 - 3, 0), Wv - U_W);
  const int rt_b = st - t + 2;   // 0..2

  // ---- Phase 1 ----
  // A-frag early (plain load, waits before first MFMA)
  const int mtile = wv & 3;
  bf16x8 afrag;
  {
    const int q_a  = mtile * 16 + l16;
    const int qh_a = h0 + (q_a >> 3), qw_a = w0 + (q_a & 7);
    const size_t qpos_a = ((size_t)(b * Tv + t) * Hv + qh_a) * Wv + qw_a;
    afrag = *(const bf16x8*)(qin + qpos_a * 128 + head * 32 + quad * 8);
  }

  // rpb -> reg (issue early), write to LDS later
  float rv0 = 0.f;
  if (tid < 845) rv0 = rpb[head * 845 + tid];

  // V: issue all loads per thread up front (one latency window)
  uint4 vv[3];
#pragma unroll
  for (int it = 0; it < 3; ++it) {
    const int j = tid + it * 1024;         // [0, 2352)
    if (j < UPOS * 4) {
      const int pos = j >> 2, c = j & 3;
      const int ta = pos / 196;
      const int r  = pos - ta * 196;
      const int rh = r / 14;
      const int ha = u_h + rh;
      const int wa = u_w + (r - rh * 14);
      const size_t gpos = (((size_t)(b * Tv + st + ta) * Hv + ha) * Wv + wa);
      vv[it] = ((const uint4*)vin)[gpos * 16 + head * 4 + c];
    }
  }

  // K: async global->LDS, source pre-swizzled so the LDS dest is linear.
  for (int ch = wv; ch < 37; ch += 16) {
    const int m = ch * 64 + lane;          // [0, 2368)
    int pos = m >> 2;
    const int slot = m & 3;
    if (pos > UPOS - 1) pos = UPOS - 1;    // dup-load; garbage masked later
    const int c  = (slot - (pos >> 2)) & 3;
    const int ta = pos / 196;
    const int r  = pos - ta * 196;
    const int rh = r / 14;
    const int ha = u_h + rh;
    const int wa = u_w + (r - rh * 14);
    const size_t gpos = (((size_t)(b * Tv + st + ta) * Hv + ha) * Wv + wa);
    gload_lds16((const uint4*)kin + gpos * 16 + head * 4 + c,
                smem + KOFF + ch * 1024 + lane * 16);
  }

  // V repack -> Vt, XOR-swizzled by (d>>3)<<5
#pragma unroll
  for (int it = 0; it < 3; ++it) {
    const int j = tid + it * 1024;
    if (j < UPOS * 4) {
      const int pos = j >> 2, c = j & 3;
      const unsigned sw = (unsigned)c << 5;          // d>>3 == c for this chunk
      const unsigned v4[4] = {vv[it].x, vv[it].y, vv[it].z, vv[it].w};
#pragma unroll
      for (int m2 = 0; m2 < 4; ++m2) {
        const int d0 = 8 * c + 2 * m2;
        const unsigned base = (unsigned)d0 * 1232 + (unsigned)pos * 2;
        *(ushort*)(smem + VTOFF + (base ^ sw))          = (ushort)(v4[m2] & 0xffffu);
        *(ushort*)(smem + VTOFF + ((base + 1232) ^ sw)) = (ushort)(v4[m2] >> 16);
      }
    }
  }
  // Vt zero pad u in [588,616) (swizzled!)
  if (tid < 448) {
    const int d = tid / 14, jj = tid - d * 14;
    const unsigned base = (unsigned)d * 1232 + 1176u + (unsigned)jj * 4;
    *(unsigned*)(smem + VTOFF + (base ^ (((unsigned)d >> 3) << 5))) = 0u;
  }
  // rpb -> LDS
  if (tid < 845) ((float*)(smem + RPBOFF))[tid] = rv0;
  __syncthreads();

  // ---- Phase 2: QK MFMAs, raw f16 scores -> P ----
  {
    ushort* ph = (ushort*)(smem + POFF2);
    for (int nt = (wv >> 2); nt < 37; nt += 4) {
      const int u = nt * 16 + l16;
      const int slot = (quad + (u >> 2)) & 3;
      const bf16x8 bfrag = *(const bf16x8*)(smem + KOFF + u * 64 + slot * 16);
      f32x4 c = {0.f, 0.f, 0.f, 0.f};
      c = __builtin_amdgcn_mfma_f32_16x16x32_bf16(afrag, bfrag, c, 0, 0, 0);
#pragma unroll
      for (int r2 = 0; r2 < 4; ++r2) {
        const int qrow = mtile * 16 + quad * 4 + r2;
        ph[(size_t)qrow * 616 + u] = f2h(c[r2]);
      }
    }
  }
  __syncthreads();

  // ---- Phase 3: windowed softmax. Each query has EXACTLY 147 valid
  // neighbors: 21 segments (ut in [0,3), a in [0,7)) of 7 consecutive u's.
  // Bias indices are consecutive: no LUT, no mask, no clamp. ----
  {
    const int qs = tid >> 4, l16s = tid & 15;
    const int qh_s = h0 + (qs >> 3), qw_s = w0 + (qs & 7);
    const int sh_s = min(max(qh_s - 3, 0), Hv - 7);
    const int sw_s = min(max(qw_s - 3, 0), Wv - 7);
    const int dh_s = sh_s - u_h, dw_s = sw_s - u_w;        // [0,7]
    const int rh0 = sh_s - qh_s + 6, rw0 = sw_s - qw_s + 6; // [0,6]
    const float* rpb_l = (const float*)(smem + RPBOFF);
    ushort* Prow = (ushort*)(smem + POFF2 + (size_t)qs * 1232);

    // segment A: s = l16s (0..15, always valid)
    const int utA = l16s / 7, aA = l16s - utA * 7;
    const int u0A = utA * 196 + (dh_s + aA) * 14 + dw_s;
    const float* bbA = rpb_l + (rt_b + utA) * 169 + (rh0 + aA) * 13 + rw0;
    // segment B: s = l16s+16 (16..20 valid -> l16s<5; ut=2, a=s-14)
    const bool hasB = (l16s < 5);
    const int aB = l16s + 2;                                // (l16s+16)-14
    const int u0B = 2 * 196 + (dh_s + aB) * 14 + dw_s;
    const float* bbB = rpb_l + (rt_b + 2) * 169 + (rh0 + aB) * 13 + rw0;

    float exA[7], exB[7];
    float sum = 0.f;
#pragma unroll
    for (int e = 0; e < 7; ++e) {
      const float s = h2f(Prow[u0A + e]) + bbA[e];
      const float ex = __expf(s);
      exA[e] = ex; sum += ex;
    }
    if (hasB) {
#pragma unroll
      for (int e = 0; e < 7; ++e) {
        const float s = h2f(Prow[u0B + e]) + bbB[e];
        const float ex = __expf(s);
        exB[e] = ex; sum += ex;
      }
    }
    sum += __shfl_xor(sum, 1);
    sum += __shfl_xor(sum, 2);
    sum += __shfl_xor(sum, 4);
    sum += __shfl_xor(sum, 8);
    if (l16s == 0) ((float*)(smem + KOFF))[qs] = 1.0f / sum;  // K region dead
    __syncthreads();            // all P-score reads complete

    // zero P wholesale (77 uint4 per row, 16 threads/row, coalesced)
    {
      uint4* Pv = (uint4*)Prow;
      for (int c = l16s; c < 77; c += 16) Pv[c] = make_uint4(0u, 0u, 0u, 0u);
    }
    __syncthreads();

    // scatter the 147 valid exps back as bf16
#pragma unroll
    for (int e = 0; e < 7; ++e) Prow[u0A + e] = f2bf16(exA[e]);
    if (hasB) {
#pragma unroll
      for (int e = 0; e < 7; ++e) Prow[u0B + e] = f2bf16(exB[e]);
    }
  }
  __syncthreads();

  // ---- Phase 4: AV MFMAs, kt-split across wave halves + LDS combine ----
  {
    const int khalf = wv >> 3;            // 0: kt 0..9, 1: kt 10..18
    const int mtA = (wv >> 1) & 3;
    const int ntA = wv & 1;
    const int dcol = ntA * 16 + l16;
    const unsigned vlocal = (unsigned)dcol * 1232;
    const unsigned vsw = ((unsigned)(dcol >> 3) & 3u) << 5;
    const unsigned char* Abase = smem + POFF2 + (size_t)(mtA * 16 + l16) * 1232;
    f32x4 o = {0.f, 0.f, 0.f, 0.f};
    const int kt0 = khalf ? 10 : 0;
    const int kt1 = khalf ? 19 : 10;
#pragma unroll 4
    for (int kt = kt0; kt < kt1; ++kt) {
      const bf16x8 a  = *(const bf16x8*)(Abase + kt * 64 + quad * 16);
      const bf16x8 bb = *(const bf16x8*)(smem + VTOFF +
                          ((vlocal + kt * 64 + quad * 16) ^ vsw));
      o = __builtin_amdgcn_mfma_f32_16x16x32_bf16(a, bb, o, 0, 0, 0);
    }
    f32x4* part = (f32x4*)(smem + KOFF + 1024);   // 8 KB scratch in dead K region
    if (khalf) part[(wv & 7) * 64 + lane] = o;
    __syncthreads();
    if (!khalf) {
      const f32x4 p2 = part[wv * 64 + lane];
      const float* invArr = (const float*)(smem + KOFF);
#pragma unroll
      for (int r2 = 0; r2 < 4; ++r2) {
        const int qrow = mtA * 16 + quad * 4 + r2;
        const float val = (o[r2] + p2[r2]) * invArr[qrow];
        const int qh2 = h0 + (qrow >> 3), qw2 = w0 + (qrow & 7);
        const size_t qp2 = ((size_t)(b * Tv + t) * Hv + qh2) * Wv + qw2;
        oout[qp2 * 128 + head * 32 + dcol] = val;
      }
    }
  }
}

// ---------------------------------------------------------------------------
extern "C" void kernel_launch(void* const* d_in, const int* in_sizes, int n_in,
                              void* d_out, int out_size, void* d_ws, size_t ws_size,
                              hipStream_t stream) {
  const float* x      = (const float*)d_in[0];
  const float* y      = (const float*)d_in[1];
  const float* qv_w   = (const float*)d_in[2];
  const float* qv_b   = (const float*)d_in[3];
  const float* k_w    = (const float*)d_in[4];
  const float* k_b    = (const float*)d_in[5];
  const float* proj_w = (const float*)d_in[6];
  const float* proj_b = (const float*)d_in[7];
  const float* rpb    = (const float*)d_in[8];
  float* out = (float*)d_out;

  const size_t elems = (size_t)MPOS * 128;        // 8,388,608
  ushort* qbuf = (ushort*)d_ws;                   // 16.8 MB (bf16, SCALE folded)
  ushort* kbuf = qbuf + elems;                    // 16.8 MB
  ushort* vbuf = kbuf + elems;                    // 16.8 MB
  float*  obuf = (float*)(vbuf + elems);          // 33.5 MB (attn out fp32)
  ushort* wqvT   = (ushort*)(obuf + elems);
  ushort* wkT    = wqvT + 256 * KPAD;
  ushort* wpT_hi = wkT + 128 * KPAD;
  ushort* wpT_lo = wpT_hi + 128 * KPAD;

  preconvert    <<<256,  256, 0, stream>>>(qv_w, k_w, proj_w, wqvT, wkT, wpT_hi, wpT_lo);
  gemm_qvk      <<<1536, 512, 0, stream>>>(x, y, wqvT, wkT, qv_b, k_b, qbuf, vbuf, kbuf);
  na3d_tile     <<<4096, 1024, 0, stream>>>(qbuf, kbuf, vbuf, rpb, obuf);
  gemm_proj_mfma<<<512,  512, 0, stream>>>(obuf, wpT_hi, wpT_lo, proj_b, out);
}